// Round 1
// baseline (9615.189 us; speedup 1.0000x reference)
//
#include <hip/hip_runtime.h>
#include <hip/hip_bf16.h>
#include <math.h>

#define HID 512
#define GATES 2048
#define BT 8192   // 32*256
#define TT 256
#define BB 32
#define DIN 768
#define NTAG 25

__device__ __forceinline__ float sigf(float x) { return 1.f / (1.f + __expf(-x)); }

// ---------------- GEMM: xz = emb @ K(dir) + bias(dir) ----------------
// M=8192, N=2048 per dir (grid.x: 16 tiles fwd, 16 tiles bwd), K=768
__global__ __launch_bounds__(256) void gemm_xz(
    const float* __restrict__ A,
    const float* __restrict__ Kf, const float* __restrict__ Kb,
    const float* __restrict__ bf, const float* __restrict__ bb,
    float* __restrict__ xzf, float* __restrict__ xzb)
{
  const int bx = blockIdx.x;   // 0..31
  const int by = blockIdx.y;   // 0..63
  const int dir = bx >> 4;
  const float* __restrict__ B = dir ? Kb : Kf;
  const float* __restrict__ bias = dir ? bb : bf;
  float* __restrict__ C = dir ? xzb : xzf;
  const int col0 = (bx & 15) * 128;
  const int row0 = by * 128;

  __shared__ float As[8][128];
  __shared__ float Bs[8][128];

  const int tid = threadIdx.x;
  const int tx = tid & 15, ty = tid >> 4;
  float acc[8][8];
  #pragma unroll
  for (int i = 0; i < 8; ++i)
    #pragma unroll
    for (int j = 0; j < 8; ++j) acc[i][j] = 0.f;

  const int arow = tid >> 1, ak4 = (tid & 1) * 4;   // A tile: 128 rows x 8 k
  const int brow = tid >> 5, bcol4 = (tid & 31) * 4; // B tile: 8 rows x 128 cols

  for (int k0 = 0; k0 < DIN; k0 += 8) {
    const float4 av = *(const float4*)(A + (size_t)(row0 + arow) * DIN + k0 + ak4);
    const float4 bv = *(const float4*)(B + (size_t)(k0 + brow) * GATES + col0 + bcol4);
    __syncthreads();
    As[ak4 + 0][arow] = av.x;
    As[ak4 + 1][arow] = av.y;
    As[ak4 + 2][arow] = av.z;
    As[ak4 + 3][arow] = av.w;
    *(float4*)&Bs[brow][bcol4] = bv;
    __syncthreads();
    #pragma unroll
    for (int kk = 0; kk < 8; ++kk) {
      float a[8], bv2[8];
      #pragma unroll
      for (int i = 0; i < 8; ++i) a[i] = As[kk][ty * 8 + i];
      #pragma unroll
      for (int j = 0; j < 8; ++j) bv2[j] = Bs[kk][tx * 8 + j];
      #pragma unroll
      for (int i = 0; i < 8; ++i)
        #pragma unroll
        for (int j = 0; j < 8; ++j) acc[i][j] = fmaf(a[i], bv2[j], acc[i][j]);
    }
  }
  #pragma unroll
  for (int i = 0; i < 8; ++i) {
    const size_t row = row0 + ty * 8 + i;
    float* outp = C + row * GATES + col0 + tx * 8;
    #pragma unroll
    for (int j = 0; j < 8; ++j) outp[j] = acc[i][j] + bias[col0 + tx * 8 + j];
  }
}

// ---------------- LSTM recurrence: one block per (batch, direction) ----------------
// 512 threads; thread tid owns hidden column tid (4 gate dots). h double-buffered in LDS,
// c in a register. dir = bid&1 so each XCD (bid%8 round-robin) sees one direction's R in L2.
__global__ __launch_bounds__(512) void lstm_rec(
    const float* __restrict__ xzf, const float* __restrict__ xzb,
    const float* __restrict__ Rf, const float* __restrict__ Rb,
    float* __restrict__ hf, float* __restrict__ hb)
{
  const int bid = blockIdx.x;
  const int dir = bid & 1;
  const int b = bid >> 1;
  const float* __restrict__ xz = dir ? xzb : xzf;
  const float* __restrict__ R = dir ? Rb : Rf;
  float* __restrict__ hout = dir ? hb : hf;

  __shared__ float hbuf[2][HID];
  const int tid = threadIdx.x;
  hbuf[0][tid] = 0.f;
  float c = 0.f;
  __syncthreads();

  for (int s = 0; s < TT; ++s) {
    const int t = dir ? (TT - 1 - s) : s;
    const float* __restrict__ xp = xz + ((size_t)b * TT + t) * GATES;
    float zi = xp[tid];
    float zf = xp[tid + 512];
    float zg = xp[tid + 1024];
    float zo = xp[tid + 1536];
    const int p = s & 1;
    const float* hp = hbuf[p];
    #pragma unroll 8
    for (int k = 0; k < HID; ++k) {
      const float hv = hp[k];  // LDS broadcast
      const float* __restrict__ Rr = R + (size_t)k * GATES;
      zi = fmaf(hv, Rr[tid], zi);
      zf = fmaf(hv, Rr[tid + 512], zf);
      zg = fmaf(hv, Rr[tid + 1024], zg);
      zo = fmaf(hv, Rr[tid + 1536], zo);
    }
    const float ig = sigf(zi), fg = sigf(zf), og = sigf(zo);
    const float gg = tanhf(zg);
    c = fg * c + ig * gg;
    const float h = og * tanhf(c);
    hbuf[1 - p][tid] = h;
    hout[((size_t)b * TT + t) * HID + tid] = h;
    __syncthreads();
  }
}

// ---------------- dense + SELU ----------------
__global__ __launch_bounds__(256) void dense_selu(
    const float* __restrict__ hf, const float* __restrict__ hb,
    const float* __restrict__ W, const float* __restrict__ bias,
    float* __restrict__ out)   // [8192][25]
{
  const int bt = blockIdx.x;
  __shared__ float h[1024];
  __shared__ float part[256];
  const int tid = threadIdx.x;
  if (tid < 128) ((float4*)h)[tid] = ((const float4*)(hf + (size_t)bt * 512))[tid];
  else           ((float4*)h)[tid] = ((const float4*)(hb + (size_t)bt * 512))[tid - 128];
  __syncthreads();
  const int n = tid >> 3, s = tid & 7;
  float acc = 0.f;
  if (n < NTAG) {
    const int k0 = s * 128;
    #pragma unroll 4
    for (int k = k0; k < k0 + 128; ++k) acc = fmaf(h[k], W[(size_t)k * NTAG + n], acc);
  }
  part[tid] = acc;
  __syncthreads();
  if (tid < NTAG) {
    float v = 0.f;
    #pragma unroll
    for (int q = 0; q < 8; ++q) v += part[tid * 8 + q];
    v += bias[tid];
    const float scale = 1.0507009873554805f, alf = 1.6732632423543772f;
    v = v > 0.f ? scale * v : scale * alf * (__expf(v) - 1.f);
    out[(size_t)bt * NTAG + tid] = v;
  }
}

// ---------------- CRF NLL: one block (64 thr) per batch ----------------
__global__ __launch_bounds__(64) void crf_kernel(
    const float* __restrict__ logits,
    const int* __restrict__ tags, const int* __restrict__ lens,
    const float* __restrict__ trans, float* __restrict__ nll)
{
  const int b = blockIdx.x;
  const int tid = threadIdx.x;
  __shared__ float tr[NTAG * NTAG];
  __shared__ float al[NTAG];
  __shared__ float red[2];
  for (int i = tid; i < NTAG * NTAG; i += 64) tr[i] = trans[i];
  __syncthreads();

  int len = lens[b];
  len = len < 1 ? 1 : (len > TT ? TT : len);
  const size_t base = (size_t)b * TT;

  // unary + binary scores
  float us = 0.f, bs = 0.f;
  for (int t = tid; t < TT; t += 64) {
    if (t < len) us += logits[(base + t) * NTAG + tags[base + t]];
    if (t >= 1 && t < len) bs += tr[tags[base + t - 1] * NTAG + tags[base + t]];
  }
  #pragma unroll
  for (int off = 32; off > 0; off >>= 1) {
    us += __shfl_down(us, off);
    bs += __shfl_down(bs, off);
  }
  if (tid == 0) { red[0] = us; red[1] = bs; }

  if (tid < NTAG) al[tid] = logits[base * NTAG + tid];
  __syncthreads();

  for (int t = 1; t < len; ++t) {   // len uniform per block
    float nv = 0.f;
    if (tid < NTAG) {
      float m = -3.4e38f;
      #pragma unroll
      for (int i = 0; i < NTAG; ++i) m = fmaxf(m, al[i] + tr[i * NTAG + tid]);
      float ss = 0.f;
      #pragma unroll
      for (int i = 0; i < NTAG; ++i) ss += __expf(al[i] + tr[i * NTAG + tid] - m);
      nv = m + __logf(ss) + logits[(base + t) * NTAG + tid];
    }
    __syncthreads();
    if (tid < NTAG) al[tid] = nv;
    __syncthreads();
  }

  if (tid == 0) {
    float m = -3.4e38f;
    for (int i = 0; i < NTAG; ++i) m = fmaxf(m, al[i]);
    float ss = 0.f;
    for (int i = 0; i < NTAG; ++i) ss += __expf(al[i] - m);
    const float logz = m + __logf(ss);
    nll[b] = -(red[0] + red[1] - logz);
  }
}

__global__ __launch_bounds__(64) void finalize(const float* __restrict__ nll, float* __restrict__ out) {
  float v = (threadIdx.x < BB) ? nll[threadIdx.x] : 0.f;
  #pragma unroll
  for (int off = 32; off > 0; off >>= 1) v += __shfl_down(v, off);
  if (threadIdx.x == 0) out[0] = v * (1.f / BB);
}

extern "C" void kernel_launch(void* const* d_in, const int* in_sizes, int n_in,
                              void* d_out, int out_size, void* d_ws, size_t ws_size,
                              hipStream_t stream) {
  const float* emb  = (const float*)d_in[0];
  const int* tags   = (const int*)d_in[1];
  const int* lens   = (const int*)d_in[2];
  const float* kf   = (const float*)d_in[3];
  const float* rf   = (const float*)d_in[4];
  const float* bf   = (const float*)d_in[5];
  const float* kb   = (const float*)d_in[6];
  const float* rb   = (const float*)d_in[7];
  const float* bb   = (const float*)d_in[8];
  const float* dw   = (const float*)d_in[9];
  const float* db   = (const float*)d_in[10];
  const float* trans= (const float*)d_in[11];
  float* out = (float*)d_out;

  float* ws  = (float*)d_ws;
  float* xzf = ws;
  float* xzb = xzf + (size_t)BT * GATES;
  float* hf  = xzb + (size_t)BT * GATES;
  float* hb  = hf + (size_t)BT * HID;
  float* nll = hb + (size_t)BT * HID;
  // total ws use: (2*8192*2048 + 2*8192*512 + 32) * 4 B ≈ 168 MB

  gemm_xz<<<dim3(32, 64), 256, 0, stream>>>(emb, kf, kb, bf, bb, xzf, xzb);
  lstm_rec<<<64, 512, 0, stream>>>(xzf, xzb, rf, rb, hf, hb);
  dense_selu<<<8192, 256, 0, stream>>>(hf, hb, dw, db, out + 1);
  crf_kernel<<<32, 64, 0, stream>>>(out + 1, tags, lens, trans, nll);
  finalize<<<1, 64, 0, stream>>>(nll, out);
}

// Round 2
// 8546.951 us; speedup vs baseline: 1.1250x; 1.1250x over previous
//
#include <hip/hip_runtime.h>
#include <hip/hip_bf16.h>
#include <math.h>

#define HID 512
#define GATES 2048
#define BT 8192   // 32*256
#define TT 256
#define BB 32
#define DIN 768
#define NTAG 25
#define UPB 4     // hidden units per persistent block

__device__ __forceinline__ float sigf(float x) { return 1.f / (1.f + __expf(-x)); }

// ---------------- GEMM: xz = emb @ K(dir) + bias(dir) ----------------
__global__ __launch_bounds__(256) void gemm_xz(
    const float* __restrict__ A,
    const float* __restrict__ Kf, const float* __restrict__ Kb,
    const float* __restrict__ bf, const float* __restrict__ bb,
    float* __restrict__ xzf, float* __restrict__ xzb)
{
  const int bx = blockIdx.x;   // 0..31
  const int by = blockIdx.y;   // 0..63
  const int dir = bx >> 4;
  const float* __restrict__ B = dir ? Kb : Kf;
  const float* __restrict__ bias = dir ? bb : bf;
  float* __restrict__ C = dir ? xzb : xzf;
  const int col0 = (bx & 15) * 128;
  const int row0 = by * 128;

  __shared__ float As[8][128];
  __shared__ float Bs[8][128];

  const int tid = threadIdx.x;
  const int tx = tid & 15, ty = tid >> 4;
  float acc[8][8];
  #pragma unroll
  for (int i = 0; i < 8; ++i)
    #pragma unroll
    for (int j = 0; j < 8; ++j) acc[i][j] = 0.f;

  const int arow = tid >> 1, ak4 = (tid & 1) * 4;
  const int brow = tid >> 5, bcol4 = (tid & 31) * 4;

  for (int k0 = 0; k0 < DIN; k0 += 8) {
    const float4 av = *(const float4*)(A + (size_t)(row0 + arow) * DIN + k0 + ak4);
    const float4 bv = *(const float4*)(B + (size_t)(k0 + brow) * GATES + col0 + bcol4);
    __syncthreads();
    As[ak4 + 0][arow] = av.x;
    As[ak4 + 1][arow] = av.y;
    As[ak4 + 2][arow] = av.z;
    As[ak4 + 3][arow] = av.w;
    *(float4*)&Bs[brow][bcol4] = bv;
    __syncthreads();
    #pragma unroll
    for (int kk = 0; kk < 8; ++kk) {
      float a[8], bv2[8];
      #pragma unroll
      for (int i = 0; i < 8; ++i) a[i] = As[kk][ty * 8 + i];
      #pragma unroll
      for (int j = 0; j < 8; ++j) bv2[j] = Bs[kk][tx * 8 + j];
      #pragma unroll
      for (int i = 0; i < 8; ++i)
        #pragma unroll
        for (int j = 0; j < 8; ++j) acc[i][j] = fmaf(a[i], bv2[j], acc[i][j]);
    }
  }
  #pragma unroll
  for (int i = 0; i < 8; ++i) {
    const size_t row = row0 + ty * 8 + i;
    float* outp = C + row * GATES + col0 + tx * 8;
    #pragma unroll
    for (int j = 0; j < 8; ++j) outp[j] = acc[i][j] + bias[col0 + tx * 8 + j];
  }
}

// ---------------- Persistent BiLSTM recurrence ----------------
// 256 blocks x 256 threads, 1 block/CU. dir = bid&1; blk = bid>>1 owns hidden
// units [blk*4, blk*4+4) x 4 gates = 16 columns for ALL 32 batches.
// Thread (c = tid&15, r = tid>>4): column j(c), R rows [r*32, r*32+32) held in
// 32 VGPRs (R read from HBM exactly once). Per step: h(s-1) staged into
// XOR-swizzled LDS, 32 batch-accumulators in regs, shfl+LDS reduce, gate math
// on tid<128 (cell state in regs), h broadcast via agent-scope stores + a
// per-direction per-step counter barrier (8 padded sub-counters).
__global__ __launch_bounds__(256, 1) void lstm_persist(
    const float* __restrict__ xzf, const float* __restrict__ xzb,
    const float* __restrict__ Rf, const float* __restrict__ Rb,
    float* __restrict__ hf, float* __restrict__ hb,
    float* __restrict__ hG,   // [2][2][32][512]  dir, parity, b, k
    int* __restrict__ ctr)    // [2][256][8][16]  dir, step, group, pad
{
  const int bid = blockIdx.x;
  const int dir = bid & 1;
  const int blk = bid >> 1;            // 0..127
  const int u0 = blk * UPB;
  const int tid = threadIdx.x;
  const int c = tid & 15;
  const int r = tid >> 4;
  const int gt = c & 3, uu = c >> 2;
  const int j = gt * HID + u0 + uu;    // gate-major column
  const int grp = blk & 7;

  const float* __restrict__ R  = dir ? Rb : Rf;
  const float* __restrict__ xz = dir ? xzb : xzf;
  float* __restrict__ hout = dir ? hb : hf;
  float* __restrict__ hGd = hG + (size_t)dir * 2 * BB * HID;
  int* __restrict__ ctrd = ctr + (size_t)dir * TT * 8 * 16;

  __shared__ float hs[BB * HID];       // 64 KB, 16B-chunk XOR-swizzled
  __shared__ float red[BB][4][17];     // wave partials (padded)
  __shared__ float zbuf[BB][20];       // gate pre-activations (padded)

  // Load R slice into registers, permuted to match the LDS chunk swizzle.
  float Rreg[32];
  {
    const int sw = r & 3;
    #pragma unroll
    for (int q = 0; q < 8; ++q) {
      const int kb = r * 32 + (q ^ sw) * 4;
      #pragma unroll
      for (int x = 0; x < 4; ++x)
        Rreg[q * 4 + x] = R[(size_t)(kb + x) * GATES + j];
    }
  }

  float cst = 0.f;                      // cell state (tid<128)
  const int b_o = tid & 31, u_o = tid >> 5;
  float4* hs4 = (float4*)hs;
  const int fb0 = tid >> 4, fb1 = (tid >> 4) + 16;

  for (int s = 0; s < TT; ++s) {
    const int t = dir ? (TT - 1 - s) : s;
    const int pp = (s + 1) & 1;        // parity holding h(s-1)

    if (s > 0) {
      if (tid < 8) {
        while (__hip_atomic_load(&ctrd[((s - 1) * 8 + tid) * 16],
                                 __ATOMIC_RELAXED, __HIP_MEMORY_SCOPE_AGENT) < 16)
          __builtin_amdgcn_s_sleep(2);
      }
      __syncthreads();
      __threadfence();                 // acquire: invalidate stale L1/L2
    }

    // stage h(s-1) -> LDS (swizzled chunks)
    {
      const float4* hsrc = (const float4*)(hGd + (size_t)pp * BB * HID);
      #pragma unroll
      for (int q2 = 0; q2 < 16; ++q2) {
        const int gidx = tid + q2 * 256;          // float4 idx 0..4095
        const float4 v = hsrc[gidx];
        const int b = gidx >> 7, k4 = gidx & 127;
        const int rr = k4 >> 3, kk4 = k4 & 7;
        hs4[b * 128 + rr * 8 + (kk4 ^ (rr & 3))] = v;
      }
    }
    __syncthreads();

    // prefetch this thread's two xz values for the finalize phase
    const float x0 = xz[((size_t)fb0 * TT + t) * GATES + j];
    const float x1 = xz[((size_t)fb1 * TT + t) * GATES + j];

    // z-loop: 32 batch accumulators, 256 ds_read_b128 + 1024 FMA
    float z[32];
    const float4* hp0 = hs4 + r * 8;
    #pragma unroll
    for (int b = 0; b < 32; ++b) {
      const float4* hp = hp0 + b * 128;
      float acc = 0.f;
      #pragma unroll
      for (int q = 0; q < 8; ++q) {
        const float4 hv = hp[q];
        acc = fmaf(hv.x, Rreg[q * 4 + 0], acc);
        acc = fmaf(hv.y, Rreg[q * 4 + 1], acc);
        acc = fmaf(hv.z, Rreg[q * 4 + 2], acc);
        acc = fmaf(hv.w, Rreg[q * 4 + 3], acc);
      }
      z[b] = acc;
    }

    // reduce over the 4 r-slices within each wave
    #pragma unroll
    for (int b = 0; b < 32; ++b) {
      z[b] += __shfl_xor(z[b], 16);
      z[b] += __shfl_xor(z[b], 32);
    }
    const int w = tid >> 6;
    if ((tid & 48) == 0) {
      #pragma unroll
      for (int b = 0; b < 32; ++b) red[b][w][c] = z[b];
    }
    __syncthreads();

    // cross-wave final sum + xz, write gate pre-activations
    {
      const float za = red[fb0][0][c] + red[fb0][1][c] + red[fb0][2][c] + red[fb0][3][c] + x0;
      const float zb2 = red[fb1][0][c] + red[fb1][1][c] + red[fb1][2][c] + red[fb1][3][c] + x1;
      zbuf[fb0][c] = za;
      zbuf[fb1][c] = zb2;
    }
    __syncthreads();

    if (tid < 128) {
      const float zi = zbuf[b_o][u_o * 4 + 0];
      const float zf = zbuf[b_o][u_o * 4 + 1];
      const float zg = zbuf[b_o][u_o * 4 + 2];
      const float zo = zbuf[b_o][u_o * 4 + 3];
      cst = sigf(zf) * cst + sigf(zi) * tanhf(zg);
      const float h = sigf(zo) * tanhf(cst);
      hout[((size_t)b_o * TT + t) * HID + u0 + u_o] = h;
      __hip_atomic_store(&hGd[(size_t)(s & 1) * BB * HID + b_o * HID + u0 + u_o], h,
                         __ATOMIC_RELAXED, __HIP_MEMORY_SCOPE_AGENT);
    }
    __syncthreads();
    if (tid == 0)
      __hip_atomic_fetch_add(&ctrd[(s * 8 + grp) * 16], 1,
                             __ATOMIC_RELEASE, __HIP_MEMORY_SCOPE_AGENT);
  }
}

// ---------------- dense + SELU ----------------
__global__ __launch_bounds__(256) void dense_selu(
    const float* __restrict__ hf, const float* __restrict__ hb,
    const float* __restrict__ W, const float* __restrict__ bias,
    float* __restrict__ out)
{
  const int bt = blockIdx.x;
  __shared__ float h[1024];
  __shared__ float part[256];
  const int tid = threadIdx.x;
  if (tid < 128) ((float4*)h)[tid] = ((const float4*)(hf + (size_t)bt * 512))[tid];
  else           ((float4*)h)[tid] = ((const float4*)(hb + (size_t)bt * 512))[tid - 128];
  __syncthreads();
  const int n = tid >> 3, s = tid & 7;
  float acc = 0.f;
  if (n < NTAG) {
    const int k0 = s * 128;
    #pragma unroll 4
    for (int k = k0; k < k0 + 128; ++k) acc = fmaf(h[k], W[(size_t)k * NTAG + n], acc);
  }
  part[tid] = acc;
  __syncthreads();
  if (tid < NTAG) {
    float v = 0.f;
    #pragma unroll
    for (int q = 0; q < 8; ++q) v += part[tid * 8 + q];
    v += bias[tid];
    const float scale = 1.0507009873554805f, alf = 1.6732632423543772f;
    v = v > 0.f ? scale * v : scale * alf * (__expf(v) - 1.f);
    out[(size_t)bt * NTAG + tid] = v;
  }
}

// ---------------- CRF NLL ----------------
__global__ __launch_bounds__(64) void crf_kernel(
    const float* __restrict__ logits,
    const int* __restrict__ tags, const int* __restrict__ lens,
    const float* __restrict__ trans, float* __restrict__ nll)
{
  const int b = blockIdx.x;
  const int tid = threadIdx.x;
  __shared__ float tr[NTAG * NTAG];
  __shared__ float al[NTAG];
  __shared__ float red[2];
  for (int i = tid; i < NTAG * NTAG; i += 64) tr[i] = trans[i];
  __syncthreads();

  int len = lens[b];
  len = len < 1 ? 1 : (len > TT ? TT : len);
  const size_t base = (size_t)b * TT;

  float us = 0.f, bs = 0.f;
  for (int t = tid; t < TT; t += 64) {
    if (t < len) us += logits[(base + t) * NTAG + tags[base + t]];
    if (t >= 1 && t < len) bs += tr[tags[base + t - 1] * NTAG + tags[base + t]];
  }
  #pragma unroll
  for (int off = 32; off > 0; off >>= 1) {
    us += __shfl_down(us, off);
    bs += __shfl_down(bs, off);
  }
  if (tid == 0) { red[0] = us; red[1] = bs; }

  if (tid < NTAG) al[tid] = logits[base * NTAG + tid];
  __syncthreads();

  for (int t = 1; t < len; ++t) {
    float nv = 0.f;
    if (tid < NTAG) {
      float m = -3.4e38f;
      #pragma unroll
      for (int i = 0; i < NTAG; ++i) m = fmaxf(m, al[i] + tr[i * NTAG + tid]);
      float ss = 0.f;
      #pragma unroll
      for (int i = 0; i < NTAG; ++i) ss += __expf(al[i] + tr[i * NTAG + tid] - m);
      nv = m + __logf(ss) + logits[(base + t) * NTAG + tid];
    }
    __syncthreads();
    if (tid < NTAG) al[tid] = nv;
    __syncthreads();
  }

  if (tid == 0) {
    float m = -3.4e38f;
    for (int i = 0; i < NTAG; ++i) m = fmaxf(m, al[i]);
    float ss = 0.f;
    for (int i = 0; i < NTAG; ++i) ss += __expf(al[i] - m);
    const float logz = m + __logf(ss);
    nll[b] = -(red[0] + red[1] - logz);
  }
}

__global__ __launch_bounds__(64) void finalize(const float* __restrict__ nll, float* __restrict__ out) {
  float v = (threadIdx.x < BB) ? nll[threadIdx.x] : 0.f;
  #pragma unroll
  for (int off = 32; off > 0; off >>= 1) v += __shfl_down(v, off);
  if (threadIdx.x == 0) out[0] = v * (1.f / BB);
}

extern "C" void kernel_launch(void* const* d_in, const int* in_sizes, int n_in,
                              void* d_out, int out_size, void* d_ws, size_t ws_size,
                              hipStream_t stream) {
  const float* emb  = (const float*)d_in[0];
  const int* tags   = (const int*)d_in[1];
  const int* lens   = (const int*)d_in[2];
  const float* kf   = (const float*)d_in[3];
  const float* rf   = (const float*)d_in[4];
  const float* bf   = (const float*)d_in[5];
  const float* kb   = (const float*)d_in[6];
  const float* rb   = (const float*)d_in[7];
  const float* bb   = (const float*)d_in[8];
  const float* dw   = (const float*)d_in[9];
  const float* db   = (const float*)d_in[10];
  const float* trans= (const float*)d_in[11];
  float* out = (float*)d_out;

  float* ws  = (float*)d_ws;
  float* xzf = ws;
  float* xzb = xzf + (size_t)BT * GATES;
  float* hf  = xzb + (size_t)BT * GATES;
  float* hb  = hf + (size_t)BT * HID;
  float* nll = hb + (size_t)BT * HID;
  float* hG  = nll + 64;                       // 2*2*32*512 = 65536 floats
  int*   ctr = (int*)(hG + 2 * 2 * BB * HID);  // 2*256*8*16 = 65536 ints

  // zero the h-exchange buffers and barrier counters (required every call)
  hipMemsetAsync(hG, 0, (size_t)(2 * 2 * BB * HID + 2 * TT * 8 * 16) * 4, stream);

  gemm_xz<<<dim3(32, 64), 256, 0, stream>>>(emb, kf, kb, bf, bb, xzf, xzb);
  lstm_persist<<<256, 256, 0, stream>>>(xzf, xzb, rf, rb, hf, hb, hG, ctr);
  dense_selu<<<8192, 256, 0, stream>>>(hf, hb, dw, db, out + 1);
  crf_kernel<<<32, 64, 0, stream>>>(out + 1, tags, lens, trans, nll);
  finalize<<<1, 64, 0, stream>>>(nll, out);
}